// Round 2
// baseline (74.335 us; speedup 1.0000x reference)
//
#include <hip/hip_runtime.h>
#include <hip/hip_bf16.h>

// BatchRankingLoss: G=511 groups of d=256 decoys; pairwise hinge ranking loss.
// loss = sum_{g,i,j} w_ij * max(0, 1 + y_ij*(o_i-o_j)) / (G*d*(d-1))
//   y_ij = -1 if t_i < t_j else +1;  w_ij = |t_i - t_j| > 0.1
//
// Symmetry: dL_ji == dL_ij (y and do both negate; product invariant; w symmetric).
// Circular offsets k=1..127 cover each unordered pair once; k=128 covers the
// diametral pairs once per endpoint. ordered_total = 2*S(1..127) + S(128).

#define DECOYS 256
#define HALF 128

__global__ __launch_bounds__(256) void brl_fused_kernel(
    const float* __restrict__ o, const float* __restrict__ t,
    float* __restrict__ ws, float* __restrict__ out,
    int G, float invN) {
    __shared__ float2 ot[2 * DECOYS];  // duplicated ring: ot[i] == ot[i+256]
    __shared__ float wsum[4];

    const int g = blockIdx.x;
    const int i = threadIdx.x;
    const int base = g * DECOYS;

    const float oi = o[base + i];
    const float ti = t[base + i];
    const float2 me = make_float2(oi, ti);
    ot[i] = me;
    ot[i + DECOYS] = me;
    __syncthreads();

    float accH = 0.0f;  // k = 1..127: each unordered pair exactly once
#pragma unroll 16
    for (int k = 1; k < HALF; ++k) {
        const float2 p = ot[i + k];          // ds_read_b64, imm offset, stride-1
        const float dt = ti - p.y;
        const float dd = oi - p.x;
        const float sdd = (dt < 0.0f) ? -dd : dd;   // y*do
        const float h = fmaxf(0.0f, 1.0f + sdd);
        accH += (fabsf(dt) > 0.1f) ? h : 0.0f;
    }
    float accD;          // k = 128: diametral pairs, once per endpoint
    {
        const float2 p = ot[i + HALF];
        const float dt = ti - p.y;
        const float dd = oi - p.x;
        const float sdd = (dt < 0.0f) ? -dd : dd;
        const float h = fmaxf(0.0f, 1.0f + sdd);
        accD = (fabsf(dt) > 0.1f) ? h : 0.0f;
    }
    float acc = 2.0f * accH + accD;

    // wave64 shuffle reduction
#pragma unroll
    for (int off = 32; off > 0; off >>= 1)
        acc += __shfl_down(acc, off, 64);

    if ((i & 63) == 0) wsum[i >> 6] = acc;
    __syncthreads();

    if (i == 0) {
        const float blockSum = wsum[0] + wsum[1] + wsum[2] + wsum[3];
        atomicAdd(&ws[0], blockSum);             // device-scope
        __threadfence();
        const unsigned int old = atomicAdd((unsigned int*)&ws[1], 1u);
        if (old == (unsigned int)(G - 1)) {
            // last block: all G adds to ws[0] are visible; atomic read-modify-0
            const float total = atomicAdd(&ws[0], 0.0f);
            out[0] = total * invN;
        }
    }
}

extern "C" void kernel_launch(void* const* d_in, const int* in_sizes, int n_in,
                              void* d_out, int out_size, void* d_ws, size_t ws_size,
                              hipStream_t stream) {
    const float* o = (const float*)d_in[0];   // input, [B,1] fp32 flat
    const float* t = (const float*)d_in[1];   // gdt_ts, [B] fp32
    float* out = (float*)d_out;

    const int B = in_sizes[1];
    const int G = B / DECOYS - 1;             // reference skips the final group
    const float invN = (float)(1.0 / ((double)G * DECOYS * (DECOYS - 1)));

    float* ws = (float*)d_ws;                 // ws[0]=accum(float), ws[1]=counter(u32)
    hipMemsetAsync(ws, 0, 2 * sizeof(float), stream);  // capture-legal memset node

    brl_fused_kernel<<<G, 256, 0, stream>>>(o, t, ws, out, G, invN);
}

// Round 3
// 61.430 us; speedup vs baseline: 1.2101x; 1.2101x over previous
//
#include <hip/hip_runtime.h>
#include <hip/hip_bf16.h>

// BatchRankingLoss: G=511 groups of d=256 decoys; pairwise hinge ranking loss.
// loss = sum_{g,i,j} w_ij * max(0, 1 + y_ij*(o_i-o_j)) / (G*d*(d-1))
//   y_ij = -1 if t_i < t_j else +1;  w_ij = |t_i - t_j| > 0.1
//
// Symmetry: dL_ji == dL_ij (y and do both negate; product invariant; w symmetric).
// Circular offsets k=1..127 cover each unordered pair once; k=128 covers the
// diametral pairs once per endpoint. ordered_total = 2*S(1..127) + S(128).
//
// R2 post-mortem: fused atomic/memset version regressed 63.9->74.3 us (extra
// fill dispatch + device-scope fence + one-cacheline atomic ping-pong across
// XCDs). Two plain kernels + d_ws partials is the fast structure.

#define DECOYS 256
#define HALF 128

__global__ __launch_bounds__(256) void brl_pair_kernel(
    const float* __restrict__ o, const float* __restrict__ t,
    float* __restrict__ partial) {
    __shared__ float2 ot[2 * DECOYS];  // duplicated ring: ot[i] == ot[i+256]
    __shared__ float wsum[4];

    const int g = blockIdx.x;
    const int i = threadIdx.x;
    const int base = g * DECOYS;

    const float oi = o[base + i];
    const float ti = t[base + i];
    const float2 me = make_float2(oi, ti);
    ot[i] = me;
    ot[i + DECOYS] = me;
    __syncthreads();

    float accH = 0.0f;  // k = 1..127: each unordered pair exactly once
#pragma unroll 16
    for (int k = 1; k < HALF; ++k) {
        const float2 p = ot[i + k];          // ds_read_b64, stride-1, conflict-free
        const float dt = ti - p.y;
        const float dd = oi - p.x;
        const float sdd = (dt < 0.0f) ? -dd : dd;   // y*do
        const float h = fmaxf(0.0f, 1.0f + sdd);
        accH += (fabsf(dt) > 0.1f) ? h : 0.0f;
    }
    float accD;          // k = 128: diametral pairs, once per endpoint
    {
        const float2 p = ot[i + HALF];
        const float dt = ti - p.y;
        const float dd = oi - p.x;
        const float sdd = (dt < 0.0f) ? -dd : dd;
        const float h = fmaxf(0.0f, 1.0f + sdd);
        accD = (fabsf(dt) > 0.1f) ? h : 0.0f;
    }
    float acc = 2.0f * accH + accD;

    // wave64 shuffle reduction
#pragma unroll
    for (int off = 32; off > 0; off >>= 1)
        acc += __shfl_down(acc, off, 64);

    if ((i & 63) == 0) wsum[i >> 6] = acc;
    __syncthreads();
    if (i == 0)
        partial[g] = wsum[0] + wsum[1] + wsum[2] + wsum[3];
}

__global__ __launch_bounds__(256) void brl_finalize_kernel(
    const float* __restrict__ partial, float* __restrict__ out,
    int G, float invN) {
    const int i = threadIdx.x;
    float acc = 0.0f;
    for (int g = i; g < G; g += 256)
        acc += partial[g];
#pragma unroll
    for (int off = 32; off > 0; off >>= 1)
        acc += __shfl_down(acc, off, 64);

    __shared__ float wsum[4];
    if ((i & 63) == 0) wsum[i >> 6] = acc;
    __syncthreads();
    if (i == 0)
        out[0] = (wsum[0] + wsum[1] + wsum[2] + wsum[3]) * invN;
}

extern "C" void kernel_launch(void* const* d_in, const int* in_sizes, int n_in,
                              void* d_out, int out_size, void* d_ws, size_t ws_size,
                              hipStream_t stream) {
    const float* o = (const float*)d_in[0];   // input, [B,1] fp32 flat
    const float* t = (const float*)d_in[1];   // gdt_ts, [B] fp32
    float* out = (float*)d_out;

    const int B = in_sizes[1];
    const int G = B / DECOYS - 1;             // reference skips the final group
    const float invN = (float)(1.0 / ((double)G * DECOYS * (DECOYS - 1)));

    float* partial = (float*)d_ws;            // G floats of scratch

    brl_pair_kernel<<<G, 256, 0, stream>>>(o, t, partial);
    brl_finalize_kernel<<<1, 256, 0, stream>>>(partial, out, G, invN);
}